// Round 1
// baseline (1733.127 us; speedup 1.0000x reference)
//
#include <hip/hip_runtime.h>
#include <math.h>

#define T_N   1000
#define L_N   1024
#define N_B   64
#define PAD   8
#define LOG2E 1.4426950408889634f
#define LN2   0.6931471805599453f
#define DT_F  0.01f

// ---------------- Kernel A: sinr[n,i] = y_ii / (y_ij + 1) ----------------
__global__ __launch_bounds__(256) void sinr_kernel(const float* __restrict__ powers,
                                                   const float* __restrict__ pathloss,
                                                   float* __restrict__ sinr) {
    __shared__ float row[L_N];
    const int i   = blockIdx.x;
    const int tid = threadIdx.x;
    for (int j = tid; j < L_N; j += 256) row[j] = pathloss[i * L_N + j];
    __syncthreads();
    const float pii  = row[i];
    const int   wv   = tid >> 6;
    const int   lane = tid & 63;
    for (int n = wv * 16; n < wv * 16 + 16; ++n) {
        const float* pr = powers + n * L_N;
        float part = 0.f;
        #pragma unroll
        for (int k = 0; k < L_N / 64; ++k)
            part += row[lane + 64 * k] * pr[lane + 64 * k];
        #pragma unroll
        for (int off = 32; off > 0; off >>= 1)
            part += __shfl_down(part, off, 64);
        if (lane == 0) {
            float yii = pii * pr[i];
            sinr[n * L_N + i] = yii / (part - yii + 1.0f);
        }
    }
}

// 16 FMAs of one 4-d chunk: acc[j] += Qp[base + j - d] * r[d]
#define CHUNK(H, L, R) do {                                                              \
    a0 = fmaf((H).x, (R).x, a0); a1 = fmaf((H).y, (R).x, a1);                            \
    a2 = fmaf((H).z, (R).x, a2); a3 = fmaf((H).w, (R).x, a3);                            \
    a0 = fmaf((L).w, (R).y, a0); a1 = fmaf((H).x, (R).y, a1);                            \
    a2 = fmaf((H).y, (R).y, a2); a3 = fmaf((H).z, (R).y, a3);                            \
    a0 = fmaf((L).z, (R).z, a0); a1 = fmaf((L).w, (R).z, a1);                            \
    a2 = fmaf((H).x, (R).z, a2); a3 = fmaf((H).y, (R).z, a3);                            \
    a0 = fmaf((L).y, (R).w, a0); a1 = fmaf((L).z, (R).w, a1);                            \
    a2 = fmaf((L).w, (R).w, a2); a3 = fmaf((H).x, (R).w, a3);                            \
} while (0)

// ---------------- Kernel B: per-link 63-step convolution scan ----------------
__global__ __launch_bounds__(256) void scan_kernel(const float* __restrict__ powers,
                                                   const float* __restrict__ sinr,
                                                   float* __restrict__ partial) {
    __shared__ __align__(16) float p2t[1024];
    __shared__ __align__(16) float Qb[2][PAD + 1024];
    __shared__ __align__(16) float rr[1024];
    __shared__ float sv[N_B];
    __shared__ float tails[N_B];

    const int l   = blockIdx.x;
    const int tid = threadIdx.x;

    if (tid < N_B) sv[tid] = sinr[tid * L_N + l];
    for (int k = tid; k < 1024; k += 256) p2t[k] = exp2f(0.01f * (float)k);
    for (int k = tid; k < PAD + 1024; k += 256) Qb[1][k] = 0.f;
    if (tid < PAD) Qb[0][tid] = 0.f;
    __syncthreads();

    // Q1[k] = 1 - exp(-(2^t - 1) * s0)
    const float s0 = sv[0] * LOG2E;
    for (int k = tid; k < 1024; k += 256) {
        float v = 0.f;
        if (k < T_N) v = 1.f - exp2f(-(p2t[k] - 1.f) * s0);
        Qb[0][PAD + k] = v;
    }
    __syncthreads();
    if (tid == 0) tails[0] = Qb[0][PAD + T_N - 1];

    const int wv     = tid >> 6;
    const int lane   = tid & 63;
    const int region = (wv + blockIdx.x) & 3;      // rotate heavy waves across SIMDs
    const int base   = region * 256 + lane * 4;    // 4 contiguous outputs per lane
    const int nch    = region * 64 + 64;           // wave-uniform chunk count

    int cb = 0;
    for (int n = 1; n < N_B; ++n) {
        // r[d] = DT * q[T-1-d],  q[k] = exp(-(2^t_k - 1) s) * 2^t_k * s * ln2
        const float s    = sv[n];
        const float sl   = s * LOG2E;
        const float smul = s * LN2 * DT_F;
        for (int d = tid; d < 1024; d += 256) {
            float v = 0.f;
            if (d < T_N) {
                float pk = p2t[T_N - 1 - d];
                v = exp2f(-(pk - 1.f) * sl) * pk * smul;
            }
            rr[d] = v;
        }
        __syncthreads();

        const float* cur = Qb[cb];
        float*       nxt = Qb[cb ^ 1];
        const float4* r4 = (const float4*)rr;
        float a0 = 0.f, a1 = 0.f, a2 = 0.f, a3 = 0.f;
        const int ib = PAD + base;
        float4 w0 = *(const float4*)&cur[ib];
        float4 w1 = *(const float4*)&cur[ib - 4];
        for (int c = 0; c < nch; c += 4) {
            const int i2 = ib - 4 * c;
            int j2 = i2 - 8;  j2 = j2 > 0 ? j2 : 0;
            int j3 = i2 - 12; j3 = j3 > 0 ? j3 : 0;
            float4 w2 = *(const float4*)&cur[j2];
            float4 w3 = *(const float4*)&cur[j3];
            float4 ra = r4[c], rb = r4[c + 1];
            CHUNK(w0, w1, ra);
            CHUNK(w1, w2, rb);
            int j4 = i2 - 16; j4 = j4 > 0 ? j4 : 0;
            int j5 = i2 - 20; j5 = j5 > 0 ? j5 : 0;
            float4 w4 = *(const float4*)&cur[j4];
            float4 w5 = *(const float4*)&cur[j5];
            float4 rc = r4[c + 2], rd = r4[c + 3];
            CHUNK(w2, w3, rc);
            CHUNK(w3, w4, rd);
            w0 = w4; w1 = w5;
        }
        if (base < T_N) {
            float4 st; st.x = a0; st.y = a1; st.z = a2; st.w = a3;
            *(float4*)&nxt[PAD + base] = st;
        }
        __syncthreads();
        if (tid == 0) tails[n] = nxt[PAD + T_N - 1];
        cb ^= 1;
    }
    __syncthreads();

    // per-link loss contribution:
    // c_l = p[0,l] + RHO + sum_{n=0..62} tails[n]*(p[n+1,l] + RHO) + LAM*tails[63]
    if (tid < N_B) {
        float tl = tails[tid];
        float term;
        if (tid < N_B - 1) term = tl * (powers[(tid + 1) * L_N + l] + 1.0f);
        else               term = tl;                       // LAM = 1
        if (tid == 0) term += powers[l] + 1.0f;             // p[0,l] + RHO*1
        #pragma unroll
        for (int off = 32; off > 0; off >>= 1)
            term += __shfl_down(term, off, 64);
        if (tid == 0) partial[l] = term;
    }
}

// ---------------- Kernel C: final deterministic reduction ----------------
__global__ __launch_bounds__(256) void reduce_kernel(const float* __restrict__ partial,
                                                     float* __restrict__ out) {
    __shared__ float red[4];
    const int tid = threadIdx.x;
    float v = partial[tid] + partial[tid + 256] + partial[tid + 512] + partial[tid + 768];
    #pragma unroll
    for (int off = 32; off > 0; off >>= 1) v += __shfl_down(v, off, 64);
    if ((tid & 63) == 0) red[tid >> 6] = v;
    __syncthreads();
    if (tid == 0) out[0] = red[0] + red[1] + red[2] + red[3];
}

extern "C" void kernel_launch(void* const* d_in, const int* in_sizes, int n_in,
                              void* d_out, int out_size, void* d_ws, size_t ws_size,
                              hipStream_t stream) {
    const float* powers   = (const float*)d_in[0];
    const float* pathloss = (const float*)d_in[1];
    float* sinr    = (float*)d_ws;            // 64*1024 floats
    float* partial = sinr + N_B * L_N;        // 1024 floats

    sinr_kernel<<<dim3(L_N), dim3(256), 0, stream>>>(powers, pathloss, sinr);
    scan_kernel<<<dim3(L_N), dim3(256), 0, stream>>>(powers, sinr, partial);
    reduce_kernel<<<dim3(1), dim3(256), 0, stream>>>(partial, (float*)d_out);
}

// Round 2
// 1662.395 us; speedup vs baseline: 1.0425x; 1.0425x over previous
//
#include <hip/hip_runtime.h>
#include <math.h>

#define T_N   1000
#define L_N   1024
#define N_B   64
#define PAD   8
#define LOG2E 1.4426950408889634f
#define LN2   0.6931471805599453f
#define DT_F  0.01f

// ---------------- Kernel A: sinr[n,i] = y_ii / (y_ij + 1) ----------------
__global__ __launch_bounds__(256) void sinr_kernel(const float* __restrict__ powers,
                                                   const float* __restrict__ pathloss,
                                                   float* __restrict__ sinr) {
    __shared__ float row[L_N];
    const int i   = blockIdx.x;
    const int tid = threadIdx.x;
    for (int j = tid; j < L_N; j += 256) row[j] = pathloss[i * L_N + j];
    __syncthreads();
    const float pii  = row[i];
    const int   wv   = tid >> 6;
    const int   lane = tid & 63;
    for (int n = wv * 16; n < wv * 16 + 16; ++n) {
        const float* pr = powers + n * L_N;
        float part = 0.f;
        #pragma unroll
        for (int k = 0; k < L_N / 64; ++k)
            part += row[lane + 64 * k] * pr[lane + 64 * k];
        #pragma unroll
        for (int off = 32; off > 0; off >>= 1)
            part += __shfl_down(part, off, 64);
        if (lane == 0) {
            float yii = pii * pr[i];
            sinr[n * L_N + i] = yii / (part - yii + 1.0f);
        }
    }
}

// acc A (float4, outputs o..o+3) += window(H = Q[o-4c .. +3], L = Q[o-4c-4 .. +3]) x R = r[4c..4c+3]
#define CH(A, H, L, R) do {                                                                \
    A.x = fmaf((H).x,(R).x,A.x); A.y = fmaf((H).y,(R).x,A.y);                              \
    A.z = fmaf((H).z,(R).x,A.z); A.w = fmaf((H).w,(R).x,A.w);                              \
    A.x = fmaf((L).w,(R).y,A.x); A.y = fmaf((H).x,(R).y,A.y);                              \
    A.z = fmaf((H).y,(R).y,A.z); A.w = fmaf((H).z,(R).y,A.w);                              \
    A.x = fmaf((L).z,(R).z,A.x); A.y = fmaf((L).w,(R).z,A.y);                              \
    A.z = fmaf((H).x,(R).z,A.z); A.w = fmaf((H).y,(R).z,A.w);                              \
    A.x = fmaf((L).y,(R).w,A.x); A.y = fmaf((L).z,(R).w,A.y);                              \
    A.z = fmaf((L).w,(R).w,A.z); A.w = fmaf((H).x,(R).w,A.w);                              \
} while (0)

__device__ __forceinline__ float4 ld4(const float* p, int i) {
    return *(const float4*)(p + i);
}

// ---------------- Kernel B: one wave per link, 16 outputs/lane ----------------
__global__ __launch_bounds__(64) void scan_kernel(const float* __restrict__ powers,
                                                  const float* __restrict__ sinr,
                                                  float* __restrict__ partial) {
    __shared__ __align__(16) float p2t[1024];
    __shared__ __align__(16) float Qb[2][PAD + 1024];
    __shared__ __align__(16) float rr[1040];          // 1024 + overrun pad for prefetch
    __shared__ float tails[N_B];

    const int l    = blockIdx.x;
    const int lane = threadIdx.x;      // 0..63, one wave

    // 2^t table
    #pragma unroll
    for (int m = 0; m < 4; ++m) {
        const int jq = lane + 64 * m;
        float4 v;
        v.x = exp2f(0.01f * (float)(4 * jq + 0));
        v.y = exp2f(0.01f * (float)(4 * jq + 1));
        v.z = exp2f(0.01f * (float)(4 * jq + 2));
        v.w = exp2f(0.01f * (float)(4 * jq + 3));
        *(float4*)&p2t[4 * jq] = v;
    }
    if (lane < PAD) { Qb[0][lane] = 0.f; Qb[1][lane] = 0.f; }
    if (lane < 16)  rr[1024 + lane] = 0.f;
    __syncthreads();

    // Q1[j] = 1 - exp2((1 - 2^t_j) * s0 * log2e)
    const float s0  = sinr[l];
    const float s0l = s0 * LOG2E;
    #pragma unroll
    for (int m = 0; m < 4; ++m) {
        const int jq = lane + 64 * m;
        float4 p = *(const float4*)&p2t[4 * jq];
        float4 v;
        v.x = 1.f - exp2f((1.f - p.x) * s0l);
        v.y = 1.f - exp2f((1.f - p.y) * s0l);
        v.z = 1.f - exp2f((1.f - p.z) * s0l);
        v.w = 1.f - exp2f((1.f - p.w) * s0l);
        *(float4*)&Qb[0][PAD + 4 * jq] = v;
        if (jq == 249) tails[0] = v.w;                // j = 999
    }
    __syncthreads();

    int cb = 0;
    for (int n = 1; n < N_B; ++n) {
        // r[d] = DT * q[T-1-d], reversed-quad reads of p2t
        const float s    = sinr[n * L_N + l];
        const float sl   = s * LOG2E;
        const float smul = s * LN2 * DT_F;
        #pragma unroll
        for (int m = 0; m < 4; ++m) {
            const int dq    = lane + 64 * m;
            const int dbase = 4 * dq;
            float4 o = make_float4(0.f, 0.f, 0.f, 0.f);
            if (dbase < T_N) {
                float4 p = *(const float4*)&p2t[996 - dbase];
                o.x = smul * p.w * exp2f((1.f - p.w) * sl);
                o.y = smul * p.z * exp2f((1.f - p.z) * sl);
                o.z = smul * p.y * exp2f((1.f - p.y) * sl);
                o.w = smul * p.x * exp2f((1.f - p.x) * sl);
            }
            *(float4*)&rr[4 * dq] = o;
        }
        __syncthreads();

        const float*  cur = Qb[cb];
        float*        nxt = Qb[cb ^ 1];
        const float4* r4  = (const float4*)rr;
        const int ib = PAD + 16 * lane;

        float4 a0 = make_float4(0,0,0,0), a1 = make_float4(0,0,0,0);
        float4 a2 = make_float4(0,0,0,0), a3 = make_float4(0,0,0,0);

        // software pipeline: current window v0..v4,n1..n4 + r0..r3
        float4 v0 = ld4(cur, ib + 12);
        float4 v1 = ld4(cur, ib + 8);
        float4 v2 = ld4(cur, ib + 4);
        float4 v3 = ld4(cur, ib);
        float4 v4 = ld4(cur, ib - 4);     // >= 4: zero pad
        int jj = ib - 8;
        float4 n1 = ld4(cur, jj > 0 ? jj : 0); jj -= 4;
        float4 n2 = ld4(cur, jj > 0 ? jj : 0); jj -= 4;
        float4 n3 = ld4(cur, jj > 0 ? jj : 0); jj -= 4;
        float4 n4 = ld4(cur, jj > 0 ? jj : 0);
        float4 r0 = r4[0], r1 = r4[1], r2 = r4[2], r3 = r4[3];

        #pragma unroll 4
        for (int c = 0; c < 256; c += 4) {
            // prefetch next round
            const int bb = ib - 4 * c;
            int j;
            j = bb - 24; float4 p1 = ld4(cur, j > 0 ? j : 0);
            j = bb - 28; float4 p2 = ld4(cur, j > 0 ? j : 0);
            j = bb - 32; float4 p3 = ld4(cur, j > 0 ? j : 0);
            j = bb - 36; float4 p4 = ld4(cur, j > 0 ? j : 0);
            float4 q0 = r4[c + 4], q1 = r4[c + 5], q2 = r4[c + 6], q3 = r4[c + 7];

            CH(a3, v0, v1, r0); CH(a2, v1, v2, r0); CH(a1, v2, v3, r0); CH(a0, v3, v4, r0);
            CH(a3, v1, v2, r1); CH(a2, v2, v3, r1); CH(a1, v3, v4, r1); CH(a0, v4, n1, r1);
            CH(a3, v2, v3, r2); CH(a2, v3, v4, r2); CH(a1, v4, n1, r2); CH(a0, n1, n2, r2);
            CH(a3, v3, v4, r3); CH(a2, v4, n1, r3); CH(a1, n1, n2, r3); CH(a0, n2, n3, r3);

            v0 = v4; v1 = n1; v2 = n2; v3 = n3; v4 = n4;
            n1 = p1; n2 = p2; n3 = p3; n4 = p4;
            r0 = q0; r1 = q1; r2 = q2; r3 = q3;
        }

        *(float4*)&nxt[ib]      = a0;
        *(float4*)&nxt[ib + 4]  = a1;
        *(float4*)&nxt[ib + 8]  = a2;
        *(float4*)&nxt[ib + 12] = a3;
        if (lane == 62) tails[n] = a1.w;              // output 999
        __syncthreads();
        cb ^= 1;
    }
    __syncthreads();

    // per-link loss contribution
    float tl   = tails[lane];
    float term = (lane < N_B - 1) ? tl * (powers[(lane + 1) * L_N + l] + 1.0f) : tl;
    if (lane == 0) term += powers[l] + 1.0f;
    #pragma unroll
    for (int off = 32; off > 0; off >>= 1) term += __shfl_down(term, off, 64);
    if (lane == 0) partial[l] = term;
}

// ---------------- Kernel C: final deterministic reduction ----------------
__global__ __launch_bounds__(256) void reduce_kernel(const float* __restrict__ partial,
                                                     float* __restrict__ out) {
    __shared__ float red[4];
    const int tid = threadIdx.x;
    float v = partial[tid] + partial[tid + 256] + partial[tid + 512] + partial[tid + 768];
    #pragma unroll
    for (int off = 32; off > 0; off >>= 1) v += __shfl_down(v, off, 64);
    if ((tid & 63) == 0) red[tid >> 6] = v;
    __syncthreads();
    if (tid == 0) out[0] = red[0] + red[1] + red[2] + red[3];
}

extern "C" void kernel_launch(void* const* d_in, const int* in_sizes, int n_in,
                              void* d_out, int out_size, void* d_ws, size_t ws_size,
                              hipStream_t stream) {
    const float* powers   = (const float*)d_in[0];
    const float* pathloss = (const float*)d_in[1];
    float* sinr    = (float*)d_ws;            // 64*1024 floats
    float* partial = sinr + N_B * L_N;        // 1024 floats

    sinr_kernel<<<dim3(L_N), dim3(256), 0, stream>>>(powers, pathloss, sinr);
    scan_kernel<<<dim3(L_N), dim3(64), 0, stream>>>(powers, sinr, partial);
    reduce_kernel<<<dim3(1), dim3(256), 0, stream>>>(partial, (float*)d_out);
}

// Round 3
// 1559.341 us; speedup vs baseline: 1.1114x; 1.0661x over previous
//
#include <hip/hip_runtime.h>
#include <math.h>

#define T_N   1000
#define L_N   1024
#define N_B   64
#define PAD   8
#define LOG2E 1.4426950408889634f
#define LN2   0.6931471805599453f
#define DT_F  0.01f

// LDS bank swizzle for Q buffers: spreads stride-8-word lane patterns across
// all 8 bank groups. Involution; identity on words < 32 (incl. zero pad).
#define SWZ(W) ((W) ^ (((W) >> 3) & 4))

// ---------------- Kernel A: sinr[n,i] = y_ii / (y_ij + 1) ----------------
__global__ __launch_bounds__(256) void sinr_kernel(const float* __restrict__ powers,
                                                   const float* __restrict__ pathloss,
                                                   float* __restrict__ sinr) {
    __shared__ float row[L_N];
    const int i   = blockIdx.x;
    const int tid = threadIdx.x;
    for (int j = tid; j < L_N; j += 256) row[j] = pathloss[i * L_N + j];
    __syncthreads();
    const float pii  = row[i];
    const int   wv   = tid >> 6;
    const int   lane = tid & 63;
    for (int n = wv * 16; n < wv * 16 + 16; ++n) {
        const float* pr = powers + n * L_N;
        float part = 0.f;
        #pragma unroll
        for (int k = 0; k < L_N / 64; ++k)
            part += row[lane + 64 * k] * pr[lane + 64 * k];
        #pragma unroll
        for (int off = 32; off > 0; off >>= 1)
            part += __shfl_down(part, off, 64);
        if (lane == 0) {
            float yii = pii * pr[i];
            sinr[n * L_N + i] = yii / (part - yii + 1.0f);
        }
    }
}

// acc A (outs quad q) += window(H = Q quad(q-c), L = Q quad(q-c-1)) x R = r quad c
#define CH(A, H, L, R) do {                                                                \
    A.x = fmaf((H).x,(R).x,A.x); A.y = fmaf((H).y,(R).x,A.y);                              \
    A.z = fmaf((H).z,(R).x,A.z); A.w = fmaf((H).w,(R).x,A.w);                              \
    A.x = fmaf((L).w,(R).y,A.x); A.y = fmaf((H).x,(R).y,A.y);                              \
    A.z = fmaf((H).y,(R).y,A.z); A.w = fmaf((H).z,(R).y,A.w);                              \
    A.x = fmaf((L).z,(R).z,A.x); A.y = fmaf((L).w,(R).z,A.y);                              \
    A.z = fmaf((H).x,(R).z,A.z); A.w = fmaf((H).y,(R).z,A.w);                              \
    A.x = fmaf((L).y,(R).w,A.x); A.y = fmaf((L).z,(R).w,A.y);                              \
    A.z = fmaf((L).w,(R).w,A.z); A.w = fmaf((H).x,(R).w,A.w);                              \
} while (0)

__device__ __forceinline__ float4 ld4s(const float* p, int W) {   // W = word idx, %4==0
    return *(const float4*)(p + SWZ(W));
}
__device__ __forceinline__ void st4s(float* p, int W, float4 v) {
    *(float4*)(p + SWZ(W)) = v;
}

// ---------------- Kernel B: 2 waves per link, 8 outputs/lane ----------------
__global__ __launch_bounds__(128, 2) void scan_kernel(const float* __restrict__ powers,
                                                      const float* __restrict__ sinr,
                                                      float* __restrict__ partial) {
    __shared__ __align__(16) float p2t[1024];
    __shared__ __align__(16) float Qb[2][PAD + 1024];
    __shared__ __align__(16) float rr[1024];
    __shared__ float sv[N_B];
    __shared__ float tails[N_B];

    const int l    = blockIdx.x;
    const int tid  = threadIdx.x;          // 0..127
    const int wv   = tid >> 6;             // wave 0 / 1
    const int lane = tid & 63;

    if (tid < N_B) sv[tid] = sinr[tid * L_N + l];
    // 2^t table: 2 quads per lane
    #pragma unroll
    for (int m = 0; m < 2; ++m) {
        const int jq = tid + 128 * m;
        float4 v;
        v.x = exp2f(0.01f * (float)(4 * jq + 0));
        v.y = exp2f(0.01f * (float)(4 * jq + 1));
        v.z = exp2f(0.01f * (float)(4 * jq + 2));
        v.w = exp2f(0.01f * (float)(4 * jq + 3));
        *(float4*)&p2t[4 * jq] = v;
    }
    if (tid < PAD) { Qb[0][tid] = 0.f; Qb[1][tid] = 0.f; }
    __syncthreads();

    // Q1[j] = 1 - exp2((1 - 2^t_j) * s0 * log2e), zero for j >= 1000
    const float s0l = sv[0] * LOG2E;
    #pragma unroll
    for (int m = 0; m < 2; ++m) {
        const int jq = tid + 128 * m;
        float4 p = *(const float4*)&p2t[4 * jq];
        float4 v = make_float4(0.f, 0.f, 0.f, 0.f);
        if (jq < 250) {
            v.x = 1.f - exp2f((1.f - p.x) * s0l);
            v.y = 1.f - exp2f((1.f - p.y) * s0l);
            v.z = 1.f - exp2f((1.f - p.z) * s0l);
            v.w = 1.f - exp2f((1.f - p.w) * s0l);
        }
        st4s(Qb[0], PAD + 4 * jq, v);
        if (jq == 249) tails[0] = v.w;     // Q1[999]
    }
    __syncthreads();

    const int obq  = 128 * wv + 2 * lane;  // lower out-quad index (0..255)
    const int ib   = PAD + 4 * obq;        // word idx of lower out quad
    const int trip = 128 * (wv + 1);       // wave-uniform tap-quad count

    int cb = 0;
    for (int n = 1; n < N_B; ++n) {
        // r[d] = DT * q[T-1-d]; r[d >= 1000] = 0
        const float s    = sv[n];
        const float sl   = s * LOG2E;
        const float smul = s * LN2 * DT_F;
        #pragma unroll
        for (int m = 0; m < 2; ++m) {
            const int dq    = tid + 128 * m;
            const int dbase = 4 * dq;
            float4 o = make_float4(0.f, 0.f, 0.f, 0.f);
            if (dbase < T_N) {
                float4 p = *(const float4*)&p2t[996 - dbase];
                o.x = smul * p.w * exp2f((1.f - p.w) * sl);
                o.y = smul * p.z * exp2f((1.f - p.z) * sl);
                o.z = smul * p.y * exp2f((1.f - p.y) * sl);
                o.w = smul * p.x * exp2f((1.f - p.x) * sl);
            }
            *(float4*)&rr[4 * dq] = o;
        }
        __syncthreads();

        const float*  cur = Qb[cb];
        float*        nxt = Qb[cb ^ 1];
        const float4* r4  = (const float4*)rr;

        float4 A0 = make_float4(0,0,0,0), A1 = make_float4(0,0,0,0);
        float4 w0 = ld4s(cur, ib + 4);     // quad obq+1
        float4 w1 = ld4s(cur, ib);         // quad obq
        float4 w2 = ld4s(cur, ib - 4);     // quad obq-1 (>=4: pad zeros)

        #pragma unroll 4
        for (int c = 0; c < trip; ++c) {
            int Wn = ib - 4 * c - 8;       // quad obq-2-c for next iter
            Wn = Wn > 0 ? Wn : 0;
            float4 wn = ld4s(cur, Wn);
            float4 rq = r4[c];
            CH(A1, w0, w1, rq);
            CH(A0, w1, w2, rq);
            w0 = w1; w1 = w2; w2 = wn;
        }

        st4s(nxt, ib,     A0);
        st4s(nxt, ib + 4, A1);
        if (obq == 248) tails[n] = A1.w;   // output 999
        __syncthreads();
        cb ^= 1;
    }
    __syncthreads();

    // per-link loss contribution (wave 0 only)
    if (tid < N_B) {
        float tl   = tails[tid];
        float term = (tid < N_B - 1) ? tl * (powers[(tid + 1) * L_N + l] + 1.0f) : tl;
        if (tid == 0) term += powers[l] + 1.0f;
        #pragma unroll
        for (int off = 32; off > 0; off >>= 1) term += __shfl_down(term, off, 64);
        if (tid == 0) partial[l] = term;
    }
}

// ---------------- Kernel C: final deterministic reduction ----------------
__global__ __launch_bounds__(256) void reduce_kernel(const float* __restrict__ partial,
                                                     float* __restrict__ out) {
    __shared__ float red[4];
    const int tid = threadIdx.x;
    float v = partial[tid] + partial[tid + 256] + partial[tid + 512] + partial[tid + 768];
    #pragma unroll
    for (int off = 32; off > 0; off >>= 1) v += __shfl_down(v, off, 64);
    if ((tid & 63) == 0) red[tid >> 6] = v;
    __syncthreads();
    if (tid == 0) out[0] = red[0] + red[1] + red[2] + red[3];
}

extern "C" void kernel_launch(void* const* d_in, const int* in_sizes, int n_in,
                              void* d_out, int out_size, void* d_ws, size_t ws_size,
                              hipStream_t stream) {
    const float* powers   = (const float*)d_in[0];
    const float* pathloss = (const float*)d_in[1];
    float* sinr    = (float*)d_ws;            // 64*1024 floats
    float* partial = sinr + N_B * L_N;        // 1024 floats

    sinr_kernel<<<dim3(L_N), dim3(256), 0, stream>>>(powers, pathloss, sinr);
    scan_kernel<<<dim3(L_N), dim3(128), 0, stream>>>(powers, sinr, partial);
    reduce_kernel<<<dim3(1), dim3(256), 0, stream>>>(partial, (float*)d_out);
}